// Round 11
// baseline (222.724 us; speedup 1.0000x reference)
//
#include <hip/hip_runtime.h>
#include <math.h>

// ---- problem constants ----
#define BB 16
#define FD 32          // F == C == 32
#define ND 200
#define TD 48
#define SD 3
#define OC 64
#define SLICE 6400            // N*C elements per (b,t)
#define TSTRIDE 4915200       // B*T*N*C elements per tensor
#define NEGBIG (-9.0e15f)
#define LOG2E 1.44269504088896340736f

typedef __attribute__((ext_vector_type(8))) short bf16x8;
typedef __attribute__((ext_vector_type(4))) float f32x4;
typedef __attribute__((ext_vector_type(4))) unsigned int u32x4;
typedef __attribute__((ext_vector_type(2))) float f32x2;
typedef __attribute__((ext_vector_type(2))) unsigned int u32x2;

// round-half-up bf16 (within 1 ulp of RNE, 1 VALU op + shift)
static __device__ __forceinline__ unsigned short f2bf(float f) {
  unsigned u = __builtin_bit_cast(unsigned, f);
  return (unsigned short)((u + 0x8000u) >> 16);
}
// exact RNE (used for hi/lo weight split so the residual is well-defined)
static __device__ __forceinline__ unsigned short f2bf_rne(float f) {
  unsigned u = __builtin_bit_cast(unsigned, f);
  return (unsigned short)((u + 0x7FFFu + ((u >> 16) & 1u)) >> 16);
}
static __device__ __forceinline__ float bf2f(unsigned short h) {
  unsigned u = ((unsigned)h) << 16;
  return __builtin_bit_cast(float, u);
}

// packed f32 pair -> bf16 pair, round-half-up, BIT-IDENTICAL to f2bf().
// R9: v_cvt_pk_bf16_f32 is NOT RNE on gfx950 (R8 precision regression).
static __device__ __forceinline__ unsigned int pk_bf16_rhu(float a, float b) {
  unsigned ua = __builtin_bit_cast(unsigned, a) + 0x8000u;
  unsigned ub = __builtin_bit_cast(unsigned, b) + 0x8000u;
#if __has_builtin(__builtin_amdgcn_perm)
  // result bytes = {ua.b2, ua.b3, ub.b2, ub.b3}  (low half = a, high = b)
  return __builtin_amdgcn_perm(ub, ua, 0x07060302u);
#else
  return (ua >> 16) | (ub & 0xFFFF0000u);
#endif
}

// hardware exp2 (v_exp_f32); inputs pre-scaled by LOG2E
#if __has_builtin(__builtin_amdgcn_exp2f)
static __device__ __forceinline__ float exp2_hw(float x) { return __builtin_amdgcn_exp2f(x); }
#else
static __device__ __forceinline__ float exp2_hw(float x) { return exp2f(x); }
#endif

// 1-ulp reciprocal (v_rcp_f32) — feeds bf16 rounding, loss invisible
#if __has_builtin(__builtin_amdgcn_rcpf)
static __device__ __forceinline__ float rcp_hw(float x) { return __builtin_amdgcn_rcpf(x); }
#else
static __device__ __forceinline__ float rcp_hw(float x) { return 1.0f / x; }
#endif

// sign-extend bit j of v to 0 / 0xFFFFFFFF (v_bfe_i32)
static __device__ __forceinline__ unsigned int sext_bit(unsigned int v, int j) {
#if __has_builtin(__builtin_amdgcn_sbfe)
  return (unsigned int)__builtin_amdgcn_sbfe((int)v, j, 1);
#else
  return 0u - ((v >> j) & 1u);
#endif
}

// merge low halfword of lo-mask with high halfword of hi-mask
static __device__ __forceinline__ unsigned int merge_hw(unsigned int lo, unsigned int hi) {
#if __has_builtin(__builtin_amdgcn_perm)
  return __builtin_amdgcn_perm(hi, lo, 0x07060100u);
#else
  return (lo & 0x0000FFFFu) | (hi & 0xFFFF0000u);
#endif
}

// One prep launch, three block ranges (R14 layout):
//   [0,800):       x (b,f,n,t) fp32 -> Xtnc (b,t,n,c) + Xntc (b,n,t,c) bf16
//   [800,1424):    adjacency -> permuted 200-bit row masks
//   [1424,1576):   W transpose->bf16, w-vector frags, mlp_w -> bf16
__global__ __launch_bounds__(256) void k_prep(
    const float* __restrict__ x, const int* __restrict__ support,
    const float* __restrict__ W1, const float* __restrict__ WK,
    const float* __restrict__ a1, const float* __restrict__ aK,
    const float* __restrict__ mw,
    unsigned short* __restrict__ Xtnc, unsigned short* __restrict__ Xntc,
    unsigned long long* __restrict__ msk,
    unsigned short* __restrict__ Wtb, unsigned short* __restrict__ Wxb,
    unsigned short* __restrict__ mwb) {
  __shared__ float sbuf[3104];  // 12.4 KB: x-stage (bf16 32x194) / w-vectors
  int bid = blockIdx.x;
  if (bid < 800) {
    int b = bid / 50, n0 = (bid % 50) * 4;
    unsigned short* sf16 = (unsigned short*)sbuf;  // [f][col], stride 194
    const float4* xv = (const float4*)x;
    for (int i = threadIdx.x; i < 1536; i += 256) {
      int nn = i / 384, rem = i % 384, f = rem / 12, q = rem % 12;
      float4 v = xv[(size_t)((b * 32 + f) * ND + n0 + nn) * 12 + q];
      unsigned short* p = &sf16[f * 194 + nn * 48 + 4 * q];
      p[0] = f2bf(v.x);
      p[1] = f2bf(v.y);
      p[2] = f2bf(v.z);
      p[3] = f2bf(v.w);
    }
    __syncthreads();
    unsigned int* dt = (unsigned int*)Xtnc;
    unsigned int* dn = (unsigned int*)Xntc;
    // pass 1: dt (b,t,n,c) — fq fast, nn mid, t slow -> 256-B runs per t
    for (int j = threadIdx.x; j < 3072; j += 256) {
      int t = j >> 6, rem = j & 63, nn = rem >> 4, fq = rem & 15;
      int col = nn * 48 + t;
      unsigned int v = (unsigned int)sf16[(2 * fq) * 194 + col] |
                       ((unsigned int)sf16[(2 * fq + 1) * 194 + col] << 16);
      dt[((size_t)(b * 48 + t) * ND + n0 + nn) * 16 + fq] = v;
    }
    // pass 2: dn (b,n,t,c) — fq fast, t mid, nn slow -> 3-KB runs per nn
    for (int j = threadIdx.x; j < 3072; j += 256) {
      int nn = j / 768, rem = j % 768, t = rem >> 4, fq = rem & 15;
      int col = nn * 48 + t;
      unsigned int v = (unsigned int)sf16[(2 * fq) * 194 + col] |
                       ((unsigned int)sf16[(2 * fq + 1) * 194 + col] << 16);
      dn[((size_t)(b * ND + n0 + nn) * 48 + t) * 16 + fq] = v;
    }
  } else if (bid < 1424) {
    int q = bid - 800;
    int si = q / 13, rg = q % 13;
    const int* adjb = support + (size_t)si * ND * ND;
    int wv = threadIdx.x >> 6, lane = threadIdx.x & 63;
#pragma unroll
    for (int j = 0; j < 4; j++) {
      int r = rg * 16 + wv * 4 + j;
      unsigned long long ws0 = 0, ws1 = 0, ws2 = 0, ws3 = 0;
      if (r < ND) {
        ws0 = __ballot(adjb[r * ND + lane] > 0);
        ws1 = __ballot(adjb[r * ND + 64 + lane] > 0);
        ws2 = __ballot(((128 + lane < ND) ? adjb[r * ND + 128 + lane] : 0) > 0);
        ws3 = __ballot(((192 + lane < ND) ? adjb[r * ND + 192 + lane] : 0) > 0);
      }
      // permute bytes: output qword qd, byte k  <-  straight byte (k*4+qd)
      if (lane < 4 && r < 208) {
        unsigned long long o = 0;
#pragma unroll
        for (int k = 0; k < 7; k++) {
          int bidx = k * 4 + lane;
          int sel = bidx >> 3;
          unsigned long long src = (sel == 0) ? ws0 : (sel == 1) ? ws1
                                 : (sel == 2) ? ws2 : ws3;
          unsigned long long byte = (src >> ((bidx & 7) * 8)) & 0xFFull;
          o |= byte << (8 * k);
        }
        msk[((size_t)si * 208 + r) * 4 + lane] = o;
      }
    }
  } else {
    int b2 = bid - 1424;
    if (b2 < 96) {
      int mat = b2 >> 4, b = b2 & 15;
      const float* src = (mat < 3) ? (W1 + (size_t)(mat * 16 + b) * 1024)
                                   : (WK + (size_t)((mat - 3) * 16 + b) * 1024);
      const float* av = (mat < 3) ? (a1 + (size_t)mat * 1024 + b * 64)
                                  : (aK + (size_t)(mat - 3) * 1024 + b * 64);
      unsigned short* dst = Wtb + (size_t)b2 * 1024;
      for (int i = threadIdx.x; i < 1024; i += 256) {
        int c = i >> 5, f = i & 31;
        dst[c * 32 + f] = f2bf_rne(src[f * 32 + c]);
      }
      // w-vectors: w1 = W@a1cols, w2 = W@a2cols (fp32), hi/lo bf16 split
      if (threadIdx.x < 32) {
        int f = threadIdx.x;
        float s1 = 0.f, s2 = 0.f;
        for (int c = 0; c < 32; c++) {
          float wfc = src[f * 32 + c];
          s1 = fmaf(wfc, av[c], s1);
          s2 = fmaf(wfc, av[32 + c], s2);
        }
        sbuf[f] = s1;
        sbuf[32 + f] = s2;
      }
      __syncthreads();
      unsigned short* wx = Wxb + (size_t)b2 * 512;  // [col][f], 16x32
      for (int i = threadIdx.x; i < 512; i += 256) {
        int col = i >> 5, f = i & 31;
        unsigned short o = 0;
        if (col < 4) {
          float s = sbuf[(col >> 1) * 32 + f];
          unsigned short hi = f2bf_rne(s);
          o = (col & 1) ? f2bf_rne(s - bf2f(hi)) : hi;
        }
        wx[i] = o;
      }
    } else {
      int i = (b2 - 96) * 256 + threadIdx.x;
      if (i < OC * 224) mwb[i] = f2bf_rne(mw[i]);
    }
  }
}

// Fused double-hop GAT per (idx,b,t) — R17 base (219.9 us total, best) +
// R18 pair-packed P-build.
// R18: unpack+product vectorized as f32x2/u32x2 ext-vector ops so the
//   backend can emit v_pk_mul_f32 (VOP3P, gfx90a+): 4 muls/pair -> 2
//   pk-muls. IEEE-identical. Stray ATT_TILE_KEEP label removed (possible
//   unroll inhibitor in R17's inner loop).
// R17: attention pass A = 3 tiles/wave; pass B = tile 12 on wave 0 only in
//   a disjoint live range. Removed waves 1-3's discarded tile-3 work.
//   VGPR 80->68, Occ 29->32%, total 225.5->219.9. NOTE: R17's profiled
//   k_gat2 (171us) contradicted the wall total (would imply ~278); treating
//   as profile artifact — if it repeats with a good total, trust wall only.
// R16: k-OUTER / tile-INNER attention: per k load Vt/f2e ONCE, unpack ONCE
//   (was 4x with ti outer). VGPR 120->80, Occ 21->29%, 130->118 us.
// SPILL SENTINEL: WRITE_SIZE must stay 57,600 KB. Register-cap path CLOSED
//   (R13); 2x-t-per-block CLOSED (R15: 216 arch VGPR -> 1 wave/SIMD).
// R11: FACTORIZED EXP — exp2(lrelu(x)) = max(exp2(x), exp2(0.2x)) over
//   x = f1+f2; per-row (E1,E1s) fp32, per-col packed bf16 (E2<<16|E2s).
// R10: epilogue staged in Y1s, cooperative uint4 writeback; rcp_hw.
// R9: pk_bf16_rhu pack (v_cvt_pk_bf16_f32 is NOT RNE on gfx950).
__global__ __launch_bounds__(256) void k_gat2(
    const unsigned short* __restrict__ Xb,   // (b,t,n,c) bf16 (padded alloc)
    const unsigned short* __restrict__ Wtb,  // 6 mats: [mat][b][c][f] bf16
    const unsigned short* __restrict__ Wxb,  // 6 mats: [mat][b][16][32] bf16
    const unsigned char* __restrict__ mskb,  // (b*SD+idx)*208*32 B, permuted
    unsigned short* __restrict__ bfp) {      // 7-tensor bf16 (b,n,t,c) pool
  int bx = blockIdx.x;
  int idx = bx / (BB * TD);
  int bt = bx % (BB * TD);
  int b = bt / TD, t = bt % TD;
  __shared__ __align__(16) unsigned short Vt[32 * 232];   // [ch][m] pad->232
  __shared__ __align__(16) unsigned short Y1s[208 * 32];  // hop out [n][c]
  __shared__ __align__(16) unsigned int f2e[224];  // packed bf16 (E2<<16|E2s)
  __shared__ __align__(16) float2 f1e[208];        // (E1, E1s) fp32
  __shared__ float SVa[64];   // [0..31] hop1 colsum, [32..63] hop2
  int tid = threadIdx.x, w = tid >> 6, lane = tid & 63;
  int cl = lane & 15, qd = lane >> 4;

  // ---- init pads ----
  if (tid < 64) SVa[tid] = 0.f;
  for (int i = tid; i < 512; i += 256) {  // Vt[:][200..231] = 0
    int cch = i >> 4, d = i & 15;
    ((unsigned int*)&Vt[cch * 232 + 200])[d] = 0u;
  }
  for (int i = tid; i < 128; i += 256)    // Y1s rows 200..207 = 0
    ((unsigned int*)&Y1s[200 * 32])[i] = 0u;
  __syncthreads();

  const unsigned char* mrow = mskb + (size_t)(b * SD + idx) * 208 * 32;
  bf16x8 ones;
#pragma unroll
  for (int j = 0; j < 8; j++) ones[j] = (short)0x3F80;  // bf16 1.0
  size_t xbase = (size_t)bt * SLICE;
  unsigned short* Yb1 = bfp + (size_t)(1 + 2 * idx) * TSTRIDE;
  unsigned short* Yb2 = bfp + (size_t)(2 + 2 * idx) * TSTRIDE;
  const float C1 = LOG2E;           // log2(e)
  const float C2 = 0.2f * LOG2E;    // alpha * log2(e)

#pragma unroll
  for (int hop = 0; hop < 2; hop++) {
    int mat = (hop == 0) ? idx : (3 + idx);
    const unsigned short* wtb = Wtb + (size_t)(mat * 16 + b) * 1024;
    const unsigned short* wxb = Wxb + (size_t)(mat * 16 + b) * 512;
    bf16x8 Bw0 = *(const bf16x8*)(wtb + cl * 32 + qd * 8);
    bf16x8 Bw1 = *(const bf16x8*)(wtb + (cl + 16) * 32 + qd * 8);
    bf16x8 Bwx = *(const bf16x8*)(wxb + cl * 32 + qd * 8);
    float* SV = SVa + hop * 32;

    // ---- Wh phase ----
    for (int ti = w; ti < 13; ti += 4) {
      bf16x8 A;
      if (hop == 0)
        A = *(const bf16x8*)(Xb + xbase + (size_t)(ti * 16 + cl) * 32 + qd * 8);
      else
        A = *(const bf16x8*)&Y1s[(ti * 16 + cl) * 32 + qd * 8];
      f32x4 d0 = {0.f, 0.f, 0.f, 0.f}, d1 = d0, d2 = d0;
      d0 = __builtin_amdgcn_mfma_f32_16x16x32_bf16(A, Bw0, d0, 0, 0, 0);
      d1 = __builtin_amdgcn_mfma_f32_16x16x32_bf16(A, Bw1, d1, 0, 0, 0);
      d2 = __builtin_amdgcn_mfma_f32_16x16x32_bf16(A, Bwx, d2, 0, 0, 0);
      int rn0 = ti * 16 + qd * 4;
      float s0 = 0.f, s1 = 0.f;
#pragma unroll
      for (int r = 0; r < 4; r++) {
        float fv = d2[r] + __shfl_xor(d2[r], 1, 64);  // cl0:f1, cl2:f2
        int rn = rn0 + r;
        if (rn < ND) {
          s0 += d0[r];
          s1 += d1[r];
          float E = exp2_hw(fv * C1);    // exp2(L*f)
          float Es = exp2_hw(fv * C2);   // exp2(0.2*L*f)
          if (cl == 0) f1e[rn] = make_float2(E, Es);
          if (cl == 2) f2e[rn] = pk_bf16_rhu(Es, E);  // low=Es, high=E
        }
      }
      if (rn0 + 3 < ND) {  // quads never straddle n=200 (200 % 4 == 0)
        uint2 q0, q1;
        q0.x = pk_bf16_rhu(d0[0], d0[1]);
        q0.y = pk_bf16_rhu(d0[2], d0[3]);
        q1.x = pk_bf16_rhu(d1[0], d1[1]);
        q1.y = pk_bf16_rhu(d1[2], d1[3]);
        *(uint2*)&Vt[cl * 232 + rn0] = q0;
        *(uint2*)&Vt[(cl + 16) * 232 + rn0] = q1;
      }
      atomicAdd(&SV[cl], s0);
      atomicAdd(&SV[cl + 16], s1);
    }
    __syncthreads();

    // shared epilogue for one attention tile
#define ATT_EPI(TI, DEN, AC0, AC1)                                        \
      {                                                                   \
        _Pragma("unroll")                                                 \
        for (int r = 0; r < 4; r++) {                                     \
          int rn = (TI) * 16 + qd * 4 + r;                                \
          if (rn < ND) {                                                  \
            float dn = DEN[r];                                            \
            float v0, v1;                                                 \
            if (dn > 0.f) {                                               \
              float iv = rcp_hw(dn);                                      \
              v0 = AC0[r] * iv;                                           \
              v1 = AC1[r] * iv;                                           \
            } else {                                                      \
              v0 = SV[cl] * (1.0f / ND);                                  \
              v1 = SV[cl + 16] * (1.0f / ND);                             \
            }                                                             \
            if (hop == 0) {                                               \
              v0 = (v0 > 0.f) ? v0 : exp2_hw(v0 * LOG2E) - 1.f;           \
              v1 = (v1 > 0.f) ? v1 : exp2_hw(v1 * LOG2E) - 1.f;           \
            } else {                                                      \
              v0 = fmaxf(v0, 0.f);                                        \
              v1 = fmaxf(v1, 0.f);                                        \
            }                                                             \
            Y1s[rn * 32 + cl] = f2bf(v0);                                 \
            Y1s[rn * 32 + cl + 16] = f2bf(v1);                            \
          }                                                               \
        }                                                                 \
      }

    // per-tile P-build: pm = max(E1*E2, E1s*E2s) via packed f32 pairs
#define ATT_TILE(EE, MB, AW)                                              \
          {                                                               \
            unsigned int mm = merge_hw(sext_bit(MB, 2 * p),               \
                                       sext_bit(MB, 2 * p + 1));          \
            f32x2 pa = EE.x * ehv;                                        \
            f32x2 pb = EE.y * elv;                                        \
            f32x2 pm = __builtin_elementwise_max(pa, pb);                 \
            AW[p] = pk_bf16_rhu(pm.x, pm.y) & mm;                         \
          }

    // ---- attention pass A: tiles w, w+4, w+8 (all 12 full tiles) ----
    {
      int r0 = w * 16 + cl, r1 = (w + 4) * 16 + cl, r2 = (w + 8) * 16 + cl;
      float2 e0 = f1e[r0], e1 = f1e[r1], e2 = f1e[r2];
      const unsigned long long mq0 =
          *(const unsigned long long*)(mrow + (size_t)r0 * 32 + qd * 8);
      const unsigned long long mq1 =
          *(const unsigned long long*)(mrow + (size_t)r1 * 32 + qd * 8);
      const unsigned long long mq2 =
          *(const unsigned long long*)(mrow + (size_t)r2 * 32 + qd * 8);
      f32x4 z4 = {0.f, 0.f, 0.f, 0.f};
      f32x4 den0 = z4, den1 = z4, den2 = z4;
      f32x4 a00 = z4, a01 = z4, a02 = z4;
      f32x4 a10 = z4, a11 = z4, a12 = z4;
#pragma unroll
      for (int k = 0; k < 7; k++) {
        int m0 = k * 32 + qd * 8;
        bf16x8 vb0 = *(const bf16x8*)&Vt[cl * 232 + m0];
        bf16x8 vb1 = *(const bf16x8*)&Vt[(cl + 16) * 232 + m0];
        u32x4 ua = *(const u32x4*)&f2e[m0];
        u32x4 ub = *(const u32x4*)&f2e[m0 + 4];
        unsigned int mb0 = (unsigned int)(mq0 >> (8 * k)) & 0xFFu;
        unsigned int mb1 = (unsigned int)(mq1 >> (8 * k)) & 0xFFu;
        unsigned int mb2 = (unsigned int)(mq2 >> (8 * k)) & 0xFFu;
        u32x4 aw0, aw1, aw2;
#pragma unroll
        for (int p = 0; p < 4; p++) {
          unsigned int u0 = (p < 2) ? ((p & 1) ? ua.z : ua.x)
                                    : ((p & 1) ? ub.z : ub.x);
          unsigned int u1 = (p < 2) ? ((p & 1) ? ua.w : ua.y)
                                    : ((p & 1) ? ub.w : ub.y);
          u32x2 uv = {u0, u1};
          f32x2 ehv = __builtin_bit_cast(f32x2, uv & 0xFFFF0000u);
          f32x2 elv = __builtin_bit_cast(f32x2, uv << 16);
          ATT_TILE(e0, mb0, aw0)
          ATT_TILE(e1, mb1, aw1)
          ATT_TILE(e2, mb2, aw2)
        }
        bf16x8 A0 = __builtin_bit_cast(bf16x8, aw0);
        bf16x8 A1 = __builtin_bit_cast(bf16x8, aw1);
        bf16x8 A2 = __builtin_bit_cast(bf16x8, aw2);
        den0 = __builtin_amdgcn_mfma_f32_16x16x32_bf16(A0, ones, den0, 0, 0, 0);
        a00 = __builtin_amdgcn_mfma_f32_16x16x32_bf16(A0, vb0, a00, 0, 0, 0);
        a10 = __builtin_amdgcn_mfma_f32_16x16x32_bf16(A0, vb1, a10, 0, 0, 0);
        den1 = __builtin_amdgcn_mfma_f32_16x16x32_bf16(A1, ones, den1, 0, 0, 0);
        a01 = __builtin_amdgcn_mfma_f32_16x16x32_bf16(A1, vb0, a01, 0, 0, 0);
        a11 = __builtin_amdgcn_mfma_f32_16x16x32_bf16(A1, vb1, a11, 0, 0, 0);
        den2 = __builtin_amdgcn_mfma_f32_16x16x32_bf16(A2, ones, den2, 0, 0, 0);
        a02 = __builtin_amdgcn_mfma_f32_16x16x32_bf16(A2, vb0, a02, 0, 0, 0);
        a12 = __builtin_amdgcn_mfma_f32_16x16x32_bf16(A2, vb1, a12, 0, 0, 0);
      }
      ATT_EPI(w, den0, a00, a10)
      ATT_EPI(w + 4, den1, a01, a11)
      ATT_EPI(w + 8, den2, a02, a12)
    }

    // ---- attention pass B: tile 12 (rows 192..207), wave 0 only ----
    if (w == 0) {
      int r3 = 192 + cl;
      float2 e3 = f1e[r3];
      const unsigned long long mq3 =
          *(const unsigned long long*)(mrow + (size_t)r3 * 32 + qd * 8);
      f32x4 z4 = {0.f, 0.f, 0.f, 0.f};
      f32x4 den3 = z4, a03 = z4, a13 = z4;
#pragma unroll
      for (int k = 0; k < 7; k++) {
        int m0 = k * 32 + qd * 8;
        bf16x8 vb0 = *(const bf16x8*)&Vt[cl * 232 + m0];
        bf16x8 vb1 = *(const bf16x8*)&Vt[(cl + 16) * 232 + m0];
        u32x4 ua = *(const u32x4*)&f2e[m0];
        u32x4 ub = *(const u32x4*)&f2e[m0 + 4];
        unsigned int mb3 = (unsigned int)(mq3 >> (8 * k)) & 0xFFu;
        u32x4 aw3;
#pragma unroll
        for (int p = 0; p < 4; p++) {
          unsigned int u0 = (p < 2) ? ((p & 1) ? ua.z : ua.x)
                                    : ((p & 1) ? ub.z : ub.x);
          unsigned int u1 = (p < 2) ? ((p & 1) ? ua.w : ua.y)
                                    : ((p & 1) ? ub.w : ub.y);
          u32x2 uv = {u0, u1};
          f32x2 ehv = __builtin_bit_cast(f32x2, uv & 0xFFFF0000u);
          f32x2 elv = __builtin_bit_cast(f32x2, uv << 16);
          ATT_TILE(e3, mb3, aw3)
        }
        bf16x8 A3 = __builtin_bit_cast(bf16x8, aw3);
        den3 = __builtin_amdgcn_mfma_f32_16x16x32_bf16(A3, ones, den3, 0, 0, 0);
        a03 = __builtin_amdgcn_mfma_f32_16x16x32_bf16(A3, vb0, a03, 0, 0, 0);
        a13 = __builtin_amdgcn_mfma_f32_16x16x32_bf16(A3, vb1, a13, 0, 0, 0);
      }
      ATT_EPI(12, den3, a03, a13)
    }
#undef ATT_TILE
#undef ATT_EPI
    __syncthreads();
    // ---- cooperative coalesced writeback: Y1s rows 0..199 -> global ----
    {
      unsigned short* Yb = (hop == 0) ? Yb1 : Yb2;
      for (int i = tid; i < 800; i += 256) {
        int rn = i >> 2, part = i & 3;
        uint4 vq = *(const uint4*)&Y1s[rn * 32 + part * 8];
        *(uint4*)(Yb + ((size_t)(b * ND + rn) * TD + t) * 32 + part * 8) = vq;
      }
    }
    // hop0 -> hop1 needs no extra barrier: hop1-Wh reads Y1s (stable) and
    // writes Vt/f1e/f2e, which no wave touches after the barrier above.
  }
}

// 1x1 conv as MFMA GEMM. R14: wave = nt (o-tile); each wave loads its 7
// B-frags ONCE into registers, loops mt x 2n. Grid 1600 x 256.
__global__ __launch_bounds__(256) void k_conv(
    const unsigned short* __restrict__ hb,   // 7 bf16 (b,n,t,c), stride TSTRIDE
    const unsigned short* __restrict__ mwb,  // (64,224) bf16
    const float* __restrict__ mb,
    float* __restrict__ out) {
  int bn = blockIdx.x;               // 16 * 100
  int b = bn / 100, n0 = (bn % 100) * 2;
  int w = threadIdx.x >> 6, lane = threadIdx.x & 63;
  int cl = lane & 15, qd = lane >> 4;
  // wave w owns output o-tile [w*16, w*16+16)
  bf16x8 bw[7];
#pragma unroll
  for (int k = 0; k < 7; k++)
    bw[k] = *(const bf16x8*)(mwb + (size_t)(w * 16 + cl) * 224 + k * 32 + qd * 8);
  int o = w * 16 + cl;
  float bias = mb[o];
#pragma unroll
  for (int nn = 0; nn < 2; nn++) {
    int n = n0 + nn;
#pragma unroll
    for (int mt = 0; mt < 3; mt++) {
      size_t abase = ((size_t)(b * ND + n) * TD + mt * 16 + cl) * 32 + qd * 8;
      f32x4 acc = {0.f, 0.f, 0.f, 0.f};
#pragma unroll
      for (int k = 0; k < 7; k++) {
        bf16x8 A = *(const bf16x8*)(hb + (size_t)k * TSTRIDE + abase);
        acc = __builtin_amdgcn_mfma_f32_16x16x32_bf16(A, bw[k], acc, 0, 0, 0);
      }
      float4 st;
      st.x = acc[0] + bias;
      st.y = acc[1] + bias;
      st.z = acc[2] + bias;
      st.w = acc[3] + bias;
      *(float4*)(out + ((size_t)(b * OC + o) * ND + n) * TD + mt * 16 + qd * 4) = st;
    }
  }
}

extern "C" void kernel_launch(void* const* d_in, const int* in_sizes, int n_in,
                              void* d_out, int out_size, void* d_ws, size_t ws_size,
                              hipStream_t stream) {
  const float* x = (const float*)d_in[0];
  const int* support = (const int*)d_in[1];
  const float* W1 = (const float*)d_in[2];
  const float* a1 = (const float*)d_in[3];
  const float* WK = (const float*)d_in[4];
  const float* aK = (const float*)d_in[5];
  const float* mw = (const float*)d_in[6];
  const float* mb = (const float*)d_in[7];
  float* out = (float*)d_out;
  char* wsb = (char*)d_ws;
  // ws layout (bytes):
  //   Xbt bf16 (b,t,n,c) +1KB pad  @ 0            9,831,424
  //   bfp 7x bf16 (b,n,t,c)        @  9,831,424  68,812,800
  //   msk 48*208*32 B              @ 78,644,224     319,488
  //   mwb bf16                     @ 78,963,712      28,672
  //   Wtb 6*16*1024 bf16           @ 78,992,384     196,608
  //   Wxb 6*16*512  bf16           @ 79,188,992      98,304   => ~79.3 MB
  unsigned short* Xbt = (unsigned short*)wsb;
  unsigned short* bfp = (unsigned short*)(wsb + 9831424);
  unsigned char* msk = (unsigned char*)(wsb + 78644224);
  unsigned short* mwb = (unsigned short*)(wsb + 78963712);
  unsigned short* Wtb = (unsigned short*)(wsb + 78992384);
  unsigned short* Wxb = (unsigned short*)(wsb + 79188992);

  k_prep<<<1576, 256, 0, stream>>>(x, support, W1, WK, a1, aK, mw, Xbt, bfp,
                                   (unsigned long long*)msk, Wtb, Wxb, mwb);
  k_gat2<<<SD * BB * TD, 256, 0, stream>>>(Xbt, Wtb, Wxb, msk, bfp);
  k_conv<<<BB * 100, 256, 0, stream>>>(bfp, mwb, mb, out);
}

// Round 12
// 217.631 us; speedup vs baseline: 1.0234x; 1.0234x over previous
//
#include <hip/hip_runtime.h>
#include <math.h>

// ---- problem constants ----
#define BB 16
#define FD 32          // F == C == 32
#define ND 200
#define TD 48
#define SD 3
#define OC 64
#define SLICE 6400            // N*C elements per (b,t)
#define TSTRIDE 4915200       // B*T*N*C elements per tensor
#define NEGBIG (-9.0e15f)
#define LOG2E 1.44269504088896340736f

typedef __attribute__((ext_vector_type(8))) short bf16x8;
typedef __attribute__((ext_vector_type(4))) float f32x4;
typedef __attribute__((ext_vector_type(4))) unsigned int u32x4;
typedef __attribute__((ext_vector_type(2))) float f32x2;
typedef __attribute__((ext_vector_type(2))) unsigned int u32x2;

// round-half-up bf16 (within 1 ulp of RNE, 1 VALU op + shift)
static __device__ __forceinline__ unsigned short f2bf(float f) {
  unsigned u = __builtin_bit_cast(unsigned, f);
  return (unsigned short)((u + 0x8000u) >> 16);
}
// exact RNE (used for hi/lo weight split so the residual is well-defined)
static __device__ __forceinline__ unsigned short f2bf_rne(float f) {
  unsigned u = __builtin_bit_cast(unsigned, f);
  return (unsigned short)((u + 0x7FFFu + ((u >> 16) & 1u)) >> 16);
}
static __device__ __forceinline__ float bf2f(unsigned short h) {
  unsigned u = ((unsigned)h) << 16;
  return __builtin_bit_cast(float, u);
}

// packed f32 pair -> bf16 pair, round-half-up, BIT-IDENTICAL to f2bf().
// R9: v_cvt_pk_bf16_f32 is NOT RNE on gfx950 (R8 precision regression).
static __device__ __forceinline__ unsigned int pk_bf16_rhu(float a, float b) {
  unsigned ua = __builtin_bit_cast(unsigned, a) + 0x8000u;
  unsigned ub = __builtin_bit_cast(unsigned, b) + 0x8000u;
#if __has_builtin(__builtin_amdgcn_perm)
  // result bytes = {ua.b2, ua.b3, ub.b2, ub.b3}  (low half = a, high = b)
  return __builtin_amdgcn_perm(ub, ua, 0x07060302u);
#else
  return (ua >> 16) | (ub & 0xFFFF0000u);
#endif
}

// hardware exp2 (v_exp_f32); inputs pre-scaled by LOG2E
#if __has_builtin(__builtin_amdgcn_exp2f)
static __device__ __forceinline__ float exp2_hw(float x) { return __builtin_amdgcn_exp2f(x); }
#else
static __device__ __forceinline__ float exp2_hw(float x) { return exp2f(x); }
#endif

// 1-ulp reciprocal (v_rcp_f32) — feeds bf16 rounding, loss invisible
#if __has_builtin(__builtin_amdgcn_rcpf)
static __device__ __forceinline__ float rcp_hw(float x) { return __builtin_amdgcn_rcpf(x); }
#else
static __device__ __forceinline__ float rcp_hw(float x) { return 1.0f / x; }
#endif

// One prep launch, three block ranges (R19 layout):
//   [0,800):       x (b,f,n,t) fp32 -> Xntc (b,n,t,c) bf16 (bfp tensor 0).
//                  R19: Xtnc DROPPED — hop-0 A-frags read from Xntc instead
//                  (64B-segment gathers, L2-hot); frees 9.8 MB for emsk.
//   [800,1424):    adjacency -> EXPANDED halfword mask table emsk:
//                  emsk[(b*SD+idx)*208 + row][w], w = k*16+qd*4+p, u32 =
//                  sext(bit(m0+2p)) | sext(bit(m0+2p+1))<<16, m0=k*32+qd*8.
//                  One u32x4 load per (k,tile) in gat2 replaces 13 VALU.
//   [1424,1576):   W transpose->bf16, w-vector frags, mlp_w -> bf16
__global__ __launch_bounds__(256) void k_prep(
    const float* __restrict__ x, const int* __restrict__ support,
    const float* __restrict__ W1, const float* __restrict__ WK,
    const float* __restrict__ a1, const float* __restrict__ aK,
    const float* __restrict__ mw,
    unsigned short* __restrict__ Xntc,      // bfp tensor 0
    unsigned int* __restrict__ emsk,        // 48*208*112 u32 = 4.47 MB
    unsigned short* __restrict__ Wtb, unsigned short* __restrict__ Wxb,
    unsigned short* __restrict__ mwb) {
  __shared__ float sbuf[3104];  // 12.4 KB: x-stage (bf16 32x194) / w-vectors
  int bid = blockIdx.x;
  if (bid < 800) {
    int b = bid / 50, n0 = (bid % 50) * 4;
    unsigned short* sf16 = (unsigned short*)sbuf;  // [f][col], stride 194
    const float4* xv = (const float4*)x;
    for (int i = threadIdx.x; i < 1536; i += 256) {
      int nn = i / 384, rem = i % 384, f = rem / 12, q = rem % 12;
      float4 v = xv[(size_t)((b * 32 + f) * ND + n0 + nn) * 12 + q];
      unsigned short* p = &sf16[f * 194 + nn * 48 + 4 * q];
      p[0] = f2bf(v.x);
      p[1] = f2bf(v.y);
      p[2] = f2bf(v.z);
      p[3] = f2bf(v.w);
    }
    __syncthreads();
    unsigned int* dn = (unsigned int*)Xntc;
    // dn (b,n,t,c) — fq fast, t mid, nn slow -> 3-KB runs per nn
    for (int j = threadIdx.x; j < 3072; j += 256) {
      int nn = j / 768, rem = j % 768, t = rem >> 4, fq = rem & 15;
      int col = nn * 48 + t;
      unsigned int v = (unsigned int)sf16[(2 * fq) * 194 + col] |
                       ((unsigned int)sf16[(2 * fq + 1) * 194 + col] << 16);
      dn[((size_t)(b * ND + n0 + nn) * 48 + t) * 16 + fq] = v;
    }
  } else if (bid < 1424) {
    int q = bid - 800;
    int si = q / 13, rg = q % 13;
    const int* adjb = support + (size_t)si * ND * ND;
    int lane = threadIdx.x & 63, wv = threadIdx.x >> 6;
#pragma unroll
    for (int j = 0; j < 4; j++) {
      int r = rg * 16 + wv * 4 + j;
      unsigned long long ws0 = 0, ws1 = 0, ws2 = 0, ws3 = 0;
      if (r < ND) {
        ws0 = __ballot(adjb[r * ND + lane] > 0);
        ws1 = __ballot(adjb[r * ND + 64 + lane] > 0);
        ws2 = __ballot(((128 + lane < ND) ? adjb[r * ND + 128 + lane] : 0) > 0);
        ws3 = __ballot(((192 + lane < ND) ? adjb[r * ND + 192 + lane] : 0) > 0);
      }
      // expand to halfword masks: word w covers elements e0=k*32+qd*8+2p, e0+1
      if (r < 208) {
#pragma unroll
        for (int half = 0; half < 2; half++) {
          int w = lane + half * 64;
          if (w < 112) {
            int k = w >> 4, rem = w & 15, qdw = rem >> 2, pw = rem & 3;
            int e0 = k * 32 + qdw * 8 + 2 * pw;  // even, <= 222
            int sel = e0 >> 6, sh = e0 & 63;
            unsigned long long src = (sel == 0) ? ws0 : (sel == 1) ? ws1
                                   : (sel == 2) ? ws2 : ws3;
            unsigned b0 = (unsigned)((src >> sh) & 1ull);
            unsigned b1 = (unsigned)((src >> (sh + 1)) & 1ull);
            emsk[((size_t)si * 208 + r) * 112 + w] =
                (b0 * 0xFFFFu) | (b1 * 0xFFFF0000u);
          }
        }
      }
    }
  } else {
    int b2 = bid - 1424;
    if (b2 < 96) {
      int mat = b2 >> 4, b = b2 & 15;
      const float* src = (mat < 3) ? (W1 + (size_t)(mat * 16 + b) * 1024)
                                   : (WK + (size_t)((mat - 3) * 16 + b) * 1024);
      const float* av = (mat < 3) ? (a1 + (size_t)mat * 1024 + b * 64)
                                  : (aK + (size_t)(mat - 3) * 1024 + b * 64);
      unsigned short* dst = Wtb + (size_t)b2 * 1024;
      for (int i = threadIdx.x; i < 1024; i += 256) {
        int c = i >> 5, f = i & 31;
        dst[c * 32 + f] = f2bf_rne(src[f * 32 + c]);
      }
      // w-vectors: w1 = W@a1cols, w2 = W@a2cols (fp32), hi/lo bf16 split
      if (threadIdx.x < 32) {
        int f = threadIdx.x;
        float s1 = 0.f, s2 = 0.f;
        for (int c = 0; c < 32; c++) {
          float wfc = src[f * 32 + c];
          s1 = fmaf(wfc, av[c], s1);
          s2 = fmaf(wfc, av[32 + c], s2);
        }
        sbuf[f] = s1;
        sbuf[32 + f] = s2;
      }
      __syncthreads();
      unsigned short* wx = Wxb + (size_t)b2 * 512;  // [col][f], 16x32
      for (int i = threadIdx.x; i < 512; i += 256) {
        int col = i >> 5, f = i & 31;
        unsigned short o = 0;
        if (col < 4) {
          float s = sbuf[(col >> 1) * 32 + f];
          unsigned short hi = f2bf_rne(s);
          o = (col & 1) ? f2bf_rne(s - bf2f(hi)) : hi;
        }
        wx[i] = o;
      }
    } else {
      int i = (b2 - 96) * 256 + threadIdx.x;
      if (i < OC * 224) mwb[i] = f2bf_rne(mw[i]);
    }
  }
}

// Fused double-hop GAT per (idx,b,t) — R18 base + R19 precomputed masks.
// R19: mask halfwords PRECOMPUTED in k_prep (emsk table, L2-resident 93 KB
//   per (b,idx) slice reused by 48 t-blocks). Per (k,tile): one u32x4 load
//   replaces 13 VALU (byte extract + 4x(2 sbfe + perm merge)) — ~273 VALU
//   per wave per hop (~20% of kernel VALU). Hop-0 A-frags now read from
//   Xntc (bfp tensor 0, 64B-segment gathers) — bit-identical values —
//   freeing the Xtnc buffer for emsk; ws stays within the proven 79.3 MB.
// R18: P-build pair-packed (f32x2 -> v_pk_mul/max). R17: 3+1 tile split
//   (pass B on wave 0 only). R16: k-outer/tile-inner (VGPR 120->80).
// SPILL SENTINEL: gat2 WRITE_SIZE must stay 57,600 KB. Register-cap path
//   CLOSED (R13); 2x-t-per-block CLOSED (R15).
// R11: FACTORIZED EXP — exp2(lrelu(x)) = max(exp2(x), exp2(0.2x)) over
//   x = f1+f2; per-row (E1,E1s) fp32, per-col packed bf16 (E2<<16|E2s).
// R10: epilogue staged in Y1s, cooperative uint4 writeback; rcp_hw.
// R9: pk_bf16_rhu pack (v_cvt_pk_bf16_f32 is NOT RNE on gfx950).
__global__ __launch_bounds__(256) void k_gat2(
    unsigned short* __restrict__ bfp,        // 7-tensor bf16 (b,n,t,c) pool
    const unsigned short* __restrict__ Wtb,  // 6 mats: [mat][b][c][f] bf16
    const unsigned short* __restrict__ Wxb,  // 6 mats: [mat][b][16][32] bf16
    const unsigned int* __restrict__ emsk) { // expanded halfword masks
  int bx = blockIdx.x;
  int idx = bx / (BB * TD);
  int bt = bx % (BB * TD);
  int b = bt / TD, t = bt % TD;
  __shared__ __align__(16) unsigned short Vt[32 * 232];   // [ch][m] pad->232
  __shared__ __align__(16) unsigned short Y1s[208 * 32];  // hop out [n][c]
  __shared__ __align__(16) unsigned int f2e[224];  // packed bf16 (E2<<16|E2s)
  __shared__ __align__(16) float2 f1e[208];        // (E1, E1s) fp32
  __shared__ float SVa[64];   // [0..31] hop1 colsum, [32..63] hop2
  int tid = threadIdx.x, w = tid >> 6, lane = tid & 63;
  int cl = lane & 15, qd = lane >> 4;

  // ---- init pads ----
  if (tid < 64) SVa[tid] = 0.f;
  for (int i = tid; i < 512; i += 256) {  // Vt[:][200..231] = 0
    int cch = i >> 4, d = i & 15;
    ((unsigned int*)&Vt[cch * 232 + 200])[d] = 0u;
  }
  for (int i = tid; i < 128; i += 256)    // Y1s rows 200..207 = 0
    ((unsigned int*)&Y1s[200 * 32])[i] = 0u;
  __syncthreads();

  const unsigned int* emb = emsk + (size_t)(b * SD + idx) * 208 * 112;
  bf16x8 ones;
#pragma unroll
  for (int j = 0; j < 8; j++) ones[j] = (short)0x3F80;  // bf16 1.0
  unsigned short* Yb1 = bfp + (size_t)(1 + 2 * idx) * TSTRIDE;
  unsigned short* Yb2 = bfp + (size_t)(2 + 2 * idx) * TSTRIDE;
  const float C1 = LOG2E;           // log2(e)
  const float C2 = 0.2f * LOG2E;    // alpha * log2(e)

#pragma unroll
  for (int hop = 0; hop < 2; hop++) {
    int mat = (hop == 0) ? idx : (3 + idx);
    const unsigned short* wtb = Wtb + (size_t)(mat * 16 + b) * 1024;
    const unsigned short* wxb = Wxb + (size_t)(mat * 16 + b) * 512;
    bf16x8 Bw0 = *(const bf16x8*)(wtb + cl * 32 + qd * 8);
    bf16x8 Bw1 = *(const bf16x8*)(wtb + (cl + 16) * 32 + qd * 8);
    bf16x8 Bwx = *(const bf16x8*)(wxb + cl * 32 + qd * 8);
    float* SV = SVa + hop * 32;

    // ---- Wh phase ----
    for (int ti = w; ti < 13; ti += 4) {
      bf16x8 A;
      if (hop == 0)
        A = *(const bf16x8*)(bfp +
              ((size_t)(b * ND + ti * 16 + cl) * TD + t) * 32 + qd * 8);
      else
        A = *(const bf16x8*)&Y1s[(ti * 16 + cl) * 32 + qd * 8];
      f32x4 d0 = {0.f, 0.f, 0.f, 0.f}, d1 = d0, d2 = d0;
      d0 = __builtin_amdgcn_mfma_f32_16x16x32_bf16(A, Bw0, d0, 0, 0, 0);
      d1 = __builtin_amdgcn_mfma_f32_16x16x32_bf16(A, Bw1, d1, 0, 0, 0);
      d2 = __builtin_amdgcn_mfma_f32_16x16x32_bf16(A, Bwx, d2, 0, 0, 0);
      int rn0 = ti * 16 + qd * 4;
      float s0 = 0.f, s1 = 0.f;
#pragma unroll
      for (int r = 0; r < 4; r++) {
        float fv = d2[r] + __shfl_xor(d2[r], 1, 64);  // cl0:f1, cl2:f2
        int rn = rn0 + r;
        if (rn < ND) {
          s0 += d0[r];
          s1 += d1[r];
          float E = exp2_hw(fv * C1);    // exp2(L*f)
          float Es = exp2_hw(fv * C2);   // exp2(0.2*L*f)
          if (cl == 0) f1e[rn] = make_float2(E, Es);
          if (cl == 2) f2e[rn] = pk_bf16_rhu(Es, E);  // low=Es, high=E
        }
      }
      if (rn0 + 3 < ND) {  // quads never straddle n=200 (200 % 4 == 0)
        uint2 q0, q1;
        q0.x = pk_bf16_rhu(d0[0], d0[1]);
        q0.y = pk_bf16_rhu(d0[2], d0[3]);
        q1.x = pk_bf16_rhu(d1[0], d1[1]);
        q1.y = pk_bf16_rhu(d1[2], d1[3]);
        *(uint2*)&Vt[cl * 232 + rn0] = q0;
        *(uint2*)&Vt[(cl + 16) * 232 + rn0] = q1;
      }
      atomicAdd(&SV[cl], s0);
      atomicAdd(&SV[cl + 16], s1);
    }
    __syncthreads();

    // shared epilogue for one attention tile
#define ATT_EPI(TI, DEN, AC0, AC1)                                        \
      {                                                                   \
        _Pragma("unroll")                                                 \
        for (int r = 0; r < 4; r++) {                                     \
          int rn = (TI) * 16 + qd * 4 + r;                                \
          if (rn < ND) {                                                  \
            float dn = DEN[r];                                            \
            float v0, v1;                                                 \
            if (dn > 0.f) {                                               \
              float iv = rcp_hw(dn);                                      \
              v0 = AC0[r] * iv;                                           \
              v1 = AC1[r] * iv;                                           \
            } else {                                                      \
              v0 = SV[cl] * (1.0f / ND);                                  \
              v1 = SV[cl + 16] * (1.0f / ND);                             \
            }                                                             \
            if (hop == 0) {                                               \
              v0 = (v0 > 0.f) ? v0 : exp2_hw(v0 * LOG2E) - 1.f;           \
              v1 = (v1 > 0.f) ? v1 : exp2_hw(v1 * LOG2E) - 1.f;           \
            } else {                                                      \
              v0 = fmaxf(v0, 0.f);                                        \
              v1 = fmaxf(v1, 0.f);                                        \
            }                                                             \
            Y1s[rn * 32 + cl] = f2bf(v0);                                 \
            Y1s[rn * 32 + cl + 16] = f2bf(v1);                            \
          }                                                               \
        }                                                                 \
      }

    // per-tile P-build: pm = max(E1*E2, E1s*E2s), precomputed mask AND
#define ATT_TILE(EE, MMV, AW)                                             \
          {                                                               \
            f32x2 pa = EE.x * ehv;                                        \
            f32x2 pb = EE.y * elv;                                        \
            f32x2 pm = __builtin_elementwise_max(pa, pb);                 \
            AW[p] = pk_bf16_rhu(pm.x, pm.y) & MMV[p];                     \
          }

    // ---- attention pass A: tiles w, w+4, w+8 (all 12 full tiles) ----
    {
      int r0 = w * 16 + cl, r1 = (w + 4) * 16 + cl, r2 = (w + 8) * 16 + cl;
      float2 e0 = f1e[r0], e1 = f1e[r1], e2 = f1e[r2];
      const unsigned int* em0 = emb + (size_t)r0 * 112 + qd * 4;
      const unsigned int* em1 = emb + (size_t)r1 * 112 + qd * 4;
      const unsigned int* em2 = emb + (size_t)r2 * 112 + qd * 4;
      f32x4 z4 = {0.f, 0.f, 0.f, 0.f};
      f32x4 den0 = z4, den1 = z4, den2 = z4;
      f32x4 a00 = z4, a01 = z4, a02 = z4;
      f32x4 a10 = z4, a11 = z4, a12 = z4;
#pragma unroll
      for (int k = 0; k < 7; k++) {
        int m0 = k * 32 + qd * 8;
        bf16x8 vb0 = *(const bf16x8*)&Vt[cl * 232 + m0];
        bf16x8 vb1 = *(const bf16x8*)&Vt[(cl + 16) * 232 + m0];
        u32x4 ua = *(const u32x4*)&f2e[m0];
        u32x4 ub = *(const u32x4*)&f2e[m0 + 4];
        u32x4 mm0 = *(const u32x4*)(em0 + k * 16);
        u32x4 mm1 = *(const u32x4*)(em1 + k * 16);
        u32x4 mm2 = *(const u32x4*)(em2 + k * 16);
        u32x4 aw0, aw1, aw2;
#pragma unroll
        for (int p = 0; p < 4; p++) {
          unsigned int u0 = (p < 2) ? ((p & 1) ? ua.z : ua.x)
                                    : ((p & 1) ? ub.z : ub.x);
          unsigned int u1 = (p < 2) ? ((p & 1) ? ua.w : ua.y)
                                    : ((p & 1) ? ub.w : ub.y);
          u32x2 uv = {u0, u1};
          f32x2 ehv = __builtin_bit_cast(f32x2, uv & 0xFFFF0000u);
          f32x2 elv = __builtin_bit_cast(f32x2, uv << 16);
          ATT_TILE(e0, mm0, aw0)
          ATT_TILE(e1, mm1, aw1)
          ATT_TILE(e2, mm2, aw2)
        }
        bf16x8 A0 = __builtin_bit_cast(bf16x8, aw0);
        bf16x8 A1 = __builtin_bit_cast(bf16x8, aw1);
        bf16x8 A2 = __builtin_bit_cast(bf16x8, aw2);
        den0 = __builtin_amdgcn_mfma_f32_16x16x32_bf16(A0, ones, den0, 0, 0, 0);
        a00 = __builtin_amdgcn_mfma_f32_16x16x32_bf16(A0, vb0, a00, 0, 0, 0);
        a10 = __builtin_amdgcn_mfma_f32_16x16x32_bf16(A0, vb1, a10, 0, 0, 0);
        den1 = __builtin_amdgcn_mfma_f32_16x16x32_bf16(A1, ones, den1, 0, 0, 0);
        a01 = __builtin_amdgcn_mfma_f32_16x16x32_bf16(A1, vb0, a01, 0, 0, 0);
        a11 = __builtin_amdgcn_mfma_f32_16x16x32_bf16(A1, vb1, a11, 0, 0, 0);
        den2 = __builtin_amdgcn_mfma_f32_16x16x32_bf16(A2, ones, den2, 0, 0, 0);
        a02 = __builtin_amdgcn_mfma_f32_16x16x32_bf16(A2, vb0, a02, 0, 0, 0);
        a12 = __builtin_amdgcn_mfma_f32_16x16x32_bf16(A2, vb1, a12, 0, 0, 0);
      }
      ATT_EPI(w, den0, a00, a10)
      ATT_EPI(w + 4, den1, a01, a11)
      ATT_EPI(w + 8, den2, a02, a12)
    }

    // ---- attention pass B: tile 12 (rows 192..207), wave 0 only ----
    if (w == 0) {
      int r3 = 192 + cl;
      float2 e3 = f1e[r3];
      const unsigned int* em3 = emb + (size_t)r3 * 112 + qd * 4;
      f32x4 z4 = {0.f, 0.f, 0.f, 0.f};
      f32x4 den3 = z4, a03 = z4, a13 = z4;
#pragma unroll
      for (int k = 0; k < 7; k++) {
        int m0 = k * 32 + qd * 8;
        bf16x8 vb0 = *(const bf16x8*)&Vt[cl * 232 + m0];
        bf16x8 vb1 = *(const bf16x8*)&Vt[(cl + 16) * 232 + m0];
        u32x4 ua = *(const u32x4*)&f2e[m0];
        u32x4 ub = *(const u32x4*)&f2e[m0 + 4];
        u32x4 mm3 = *(const u32x4*)(em3 + k * 16);
        u32x4 aw3;
#pragma unroll
        for (int p = 0; p < 4; p++) {
          unsigned int u0 = (p < 2) ? ((p & 1) ? ua.z : ua.x)
                                    : ((p & 1) ? ub.z : ub.x);
          unsigned int u1 = (p < 2) ? ((p & 1) ? ua.w : ua.y)
                                    : ((p & 1) ? ub.w : ub.y);
          u32x2 uv = {u0, u1};
          f32x2 ehv = __builtin_bit_cast(f32x2, uv & 0xFFFF0000u);
          f32x2 elv = __builtin_bit_cast(f32x2, uv << 16);
          ATT_TILE(e3, mm3, aw3)
        }
        bf16x8 A3 = __builtin_bit_cast(bf16x8, aw3);
        den3 = __builtin_amdgcn_mfma_f32_16x16x32_bf16(A3, ones, den3, 0, 0, 0);
        a03 = __builtin_amdgcn_mfma_f32_16x16x32_bf16(A3, vb0, a03, 0, 0, 0);
        a13 = __builtin_amdgcn_mfma_f32_16x16x32_bf16(A3, vb1, a13, 0, 0, 0);
      }
      ATT_EPI(12, den3, a03, a13)
    }
#undef ATT_TILE
#undef ATT_EPI
    __syncthreads();
    // ---- cooperative coalesced writeback: Y1s rows 0..199 -> global ----
    {
      unsigned short* Yb = (hop == 0) ? Yb1 : Yb2;
      for (int i = tid; i < 800; i += 256) {
        int rn = i >> 2, part = i & 3;
        uint4 vq = *(const uint4*)&Y1s[rn * 32 + part * 8];
        *(uint4*)(Yb + ((size_t)(b * ND + rn) * TD + t) * 32 + part * 8) = vq;
      }
    }
    // hop0 -> hop1 needs no extra barrier: hop1-Wh reads Y1s (stable) and
    // writes Vt/f1e/f2e, which no wave touches after the barrier above.
  }
}

// 1x1 conv as MFMA GEMM. R14: wave = nt (o-tile); each wave loads its 7
// B-frags ONCE into registers, loops mt x 2n. Grid 1600 x 256.
__global__ __launch_bounds__(256) void k_conv(
    const unsigned short* __restrict__ hb,   // 7 bf16 (b,n,t,c), stride TSTRIDE
    const unsigned short* __restrict__ mwb,  // (64,224) bf16
    const float* __restrict__ mb,
    float* __restrict__ out) {
  int bn = blockIdx.x;               // 16 * 100
  int b = bn / 100, n0 = (bn % 100) * 2;
  int w = threadIdx.x >> 6, lane = threadIdx.x & 63;
  int cl = lane & 15, qd = lane >> 4;
  // wave w owns output o-tile [w*16, w*16+16)
  bf16x8 bw[7];
#pragma unroll
  for (int k = 0; k < 7; k++)
    bw[k] = *(const bf16x8*)(mwb + (size_t)(w * 16 + cl) * 224 + k * 32 + qd * 8);
  int o = w * 16 + cl;
  float bias = mb[o];
#pragma unroll
  for (int nn = 0; nn < 2; nn++) {
    int n = n0 + nn;
#pragma unroll
    for (int mt = 0; mt < 3; mt++) {
      size_t abase = ((size_t)(b * ND + n) * TD + mt * 16 + cl) * 32 + qd * 8;
      f32x4 acc = {0.f, 0.f, 0.f, 0.f};
#pragma unroll
      for (int k = 0; k < 7; k++) {
        bf16x8 A = *(const bf16x8*)(hb + (size_t)k * TSTRIDE + abase);
        acc = __builtin_amdgcn_mfma_f32_16x16x32_bf16(A, bw[k], acc, 0, 0, 0);
      }
      float4 st;
      st.x = acc[0] + bias;
      st.y = acc[1] + bias;
      st.z = acc[2] + bias;
      st.w = acc[3] + bias;
      *(float4*)(out + ((size_t)(b * OC + o) * ND + n) * TD + mt * 16 + qd * 4) = st;
    }
  }
}

extern "C" void kernel_launch(void* const* d_in, const int* in_sizes, int n_in,
                              void* d_out, int out_size, void* d_ws, size_t ws_size,
                              hipStream_t stream) {
  const float* x = (const float*)d_in[0];
  const int* support = (const int*)d_in[1];
  const float* W1 = (const float*)d_in[2];
  const float* a1 = (const float*)d_in[3];
  const float* WK = (const float*)d_in[4];
  const float* aK = (const float*)d_in[5];
  const float* mw = (const float*)d_in[6];
  const float* mb = (const float*)d_in[7];
  float* out = (float*)d_out;
  char* wsb = (char*)d_ws;
  // ws layout (bytes) — R19:
  //   emsk u32 48*208*112          @ 0             4,472,832  (was Xbt)
  //   bfp 7x bf16 (b,n,t,c)        @  9,831,424   68,812,800
  //   mwb bf16                     @ 78,963,712       28,672
  //   Wtb 6*16*1024 bf16           @ 78,992,384      196,608
  //   Wxb 6*16*512  bf16           @ 79,188,992       98,304  => ~79.3 MB
  unsigned int* emsk = (unsigned int*)wsb;
  unsigned short* bfp = (unsigned short*)(wsb + 9831424);
  unsigned short* mwb = (unsigned short*)(wsb + 78963712);
  unsigned short* Wtb = (unsigned short*)(wsb + 78992384);
  unsigned short* Wxb = (unsigned short*)(wsb + 79188992);

  k_prep<<<1576, 256, 0, stream>>>(x, support, W1, WK, a1, aK, mw, bfp, emsk,
                                   Wtb, Wxb, mwb);
  k_gat2<<<SD * BB * TD, 256, 0, stream>>>(bfp, Wtb, Wxb, emsk);
  k_conv<<<BB * 100, 256, 0, stream>>>(bfp, mwb, mb, out);
}